// Round 2
// baseline (991.249 us; speedup 1.0000x reference)
//
#include <hip/hip_runtime.h>
#include <hip/hip_bf16.h>

// ---------------- problem constants ----------------
#define BB     2
#define NN     2065          // N_PATCH + N_TABLE + N_CLS
#define NPAD   2112          // 33*64
#define HH     8
#define DD     64
#define EE     512
#define MROWS  (BB*NN)       // 4130
#define NPATCH 2048
#define NTAB   16
#define SCALEF 0.125f
#define EPSF   1e-6f

typedef __bf16 bf16;
typedef bf16  bf16x8 __attribute__((ext_vector_type(8)));
typedef bf16  bf16x4v __attribute__((ext_vector_type(4)));
typedef float f32x4  __attribute__((ext_vector_type(4)));

#define LDS_STRIDE 72   // 64 + 8 pad bf16 (144 B rows, 16B aligned)

// ---------------- prep kernels ----------------
__global__ __launch_bounds__(256) void k_zero(uint4* __restrict__ p, int n4) {
    int i = blockIdx.x * 256 + threadIdx.x;
    if (i < n4) { uint4 z = {0,0,0,0}; p[i] = z; }
}

__global__ __launch_bounds__(256) void k_cvt(const float* __restrict__ x,
                                             bf16* __restrict__ o, int n4) {
    int i = blockIdx.x * 256 + threadIdx.x;
    if (i < n4) {
        float4 v = ((const float4*)x)[i];
        bf16x4v r;
        r[0] = (bf16)v.x; r[1] = (bf16)v.y; r[2] = (bf16)v.z; r[3] = (bf16)v.w;
        *(bf16x4v*)(o + 4*(size_t)i) = r;
    }
}

// out[c*512 + k] = in[k*C + c]   (weights have 512 rows)
__global__ __launch_bounds__(256) void k_transcvt(const float* __restrict__ w,
                                                  bf16* __restrict__ o,
                                                  int C, int total) {
    int i = blockIdx.x * 256 + threadIdx.x;
    if (i < total) {
        int k = i & 511, c = i >> 9;
        o[i] = (bf16)w[(size_t)k * C + c];
    }
}

// ---------------- GEMM1: qkv = x @ w_qkv + b ; scatter into Qh/Kh/Vt ----------------
__global__ __launch_bounds__(256) void k_gemm_qkv(
    const bf16* __restrict__ xb, const bf16* __restrict__ wt,
    const float* __restrict__ bias,
    bf16* __restrict__ Qh, bf16* __restrict__ Kh, bf16* __restrict__ Vt)
{
    __shared__ bf16 As[64][LDS_STRIDE];
    __shared__ bf16 Bs[64][LDS_STRIDE];
    int t = threadIdx.x;
    int w = t >> 6, l = t & 63, l15 = l & 15, quad = l >> 4;
    int m0 = blockIdx.y * 64, c0 = blockIdx.x * 64;
    int srow = t >> 2, sseg = (t & 3) * 16;
    f32x4 acc[4] = {};

    for (int kk = 0; kk < 512; kk += 64) {
        {
            int m = m0 + srow;
            uint4 v0 = {0,0,0,0}, v1 = {0,0,0,0};
            if (m < MROWS) {
                const uint4* src = (const uint4*)(xb + (size_t)m*512 + kk + sseg);
                v0 = src[0]; v1 = src[1];
            }
            *(uint4*)&As[srow][sseg]     = v0;
            *(uint4*)&As[srow][sseg + 8] = v1;
            const uint4* bs = (const uint4*)(wt + (size_t)(c0 + srow)*512 + kk + sseg);
            *(uint4*)&Bs[srow][sseg]     = bs[0];
            *(uint4*)&Bs[srow][sseg + 8] = bs[1];
        }
        __syncthreads();
        #pragma unroll
        for (int kh = 0; kh < 2; kh++) {
            bf16x8 a = *(const bf16x8*)&As[w*16 + l15][kh*32 + quad*8];
            #pragma unroll
            for (int c = 0; c < 4; c++) {
                bf16x8 b = *(const bf16x8*)&Bs[c*16 + l15][kh*32 + quad*8];
                acc[c] = __builtin_amdgcn_mfma_f32_16x16x32_bf16(a, b, acc[c], 0, 0, 0);
            }
        }
        __syncthreads();
    }

    int which = c0 >> 9;             // 0=q 1=k 2=v (uniform per block)
    int h = (c0 & 511) >> 6;         // uniform per block
    #pragma unroll
    for (int c = 0; c < 4; c++) {
        int d  = (c0 & 63) + c*16 + l15;   // c0 is mult of 64 -> d = c*16+l15
        float bv = bias[c0 + c*16 + l15];
        #pragma unroll
        for (int r = 0; r < 4; r++) {
            int m = m0 + w*16 + quad*4 + r;
            if (m >= MROWS) continue;
            int b_ = m / NN, n = m - b_ * NN;
            int bh = b_ * 8 + h;
            float v = acc[c][r] + bv;
            if (which == 0)      Qh[(size_t)(bh*NPAD + n)*64 + d] = (bf16)v;
            else if (which == 1) Kh[(size_t)(bh*NPAD + n)*64 + d] = (bf16)v;
            else                 Vt[((size_t)bh*64 + d)*NPAD + n] = (bf16)v;
        }
    }
}

// ---------------- attention pass 1: A_raw + per-row coefficients ----------------
// Barrier-free, LDS-free: Q fragments hoisted; K fragments loaded directly from
// global in B-frag layout with 1-deep register prefetch (manual unroll-2, no copies).
#define A1_LOADK(dst, ktv) do {                                                    \
    const bf16* kbn_ = kb + (size_t)(ktv)*4096;                                    \
    _Pragma("unroll")                                                              \
    for (int c = 0; c < 4; ++c) {                                                  \
        dst[2*c]   = *(const bf16x8*)(kbn_ + c*1024);                              \
        dst[2*c+1] = *(const bf16x8*)(kbn_ + c*1024 + 32);                         \
    }                                                                              \
} while (0)

#define A1_BODY(ktv, kf) do {                                                      \
    f32x4 acc_[4] = {};                                                            \
    _Pragma("unroll")                                                              \
    for (int c = 0; c < 4; ++c) {                                                  \
        acc_[c] = __builtin_amdgcn_mfma_f32_16x16x32_bf16(qa0, kf[2*c],   acc_[c], 0, 0, 0); \
        acc_[c] = __builtin_amdgcn_mfma_f32_16x16x32_bf16(qa1, kf[2*c+1], acc_[c], 0, 0, 0); \
    }                                                                              \
    _Pragma("unroll")                                                              \
    for (int c = 0; c < 4; ++c) {                                                  \
        int col_ = (ktv)*64 + c*16 + l15;                                          \
        bool vc_ = col_ < NN;                                                      \
        _Pragma("unroll")                                                          \
        for (int r = 0; r < 4; ++r) {                                              \
            float val_ = acc_[c][r] * SCALEF;                                      \
            float e_ = __expf(val_);                                               \
            if (col_ < NPATCH)            { sp[r] += val_; sep[r]  += e_; }        \
            else if (col_ < NPATCH+NTAB)  { st[r] += val_; set_[r] += e_; }        \
            else if (col_ == NPATCH+NTAB) { cv[r] = val_; }                        \
            if (vc_ && vr[r]) Araw[rbase[r] + col_] = val_;                        \
        }                                                                          \
    }                                                                              \
} while (0)

__global__ __launch_bounds__(256) void k_attn1(
    const bf16* __restrict__ Qh, const bf16* __restrict__ Kh,
    float* __restrict__ Araw, float4* __restrict__ stats)
{
    int t = threadIdx.x;
    int w = t >> 6, l = t & 63, l15 = l & 15, quad = l >> 4;
    int n0 = blockIdx.x * 64;
    int bh = blockIdx.y;

    const bf16* qp = Qh + ((size_t)(bh*NPAD) + n0 + w*16 + l15)*64 + quad*8;
    bf16x8 qa0 = *(const bf16x8*)qp;
    bf16x8 qa1 = *(const bf16x8*)(qp + 32);

    // per-lane K base: key-row = kt*64 + c*16 + l15, elem = kh*32 + quad*8
    const bf16* kb = Kh + (size_t)(bh*NPAD)*64 + (size_t)(l15*64) + quad*8;

    int nrow[4]; bool vr[4]; size_t rbase[4];
    #pragma unroll
    for (int r = 0; r < 4; ++r) {
        nrow[r] = n0 + w*16 + quad*4 + r;
        vr[r] = nrow[r] < NN;
        rbase[r] = ((size_t)(bh*NN + nrow[r]))*NN;
    }

    float sp[4]  = {0,0,0,0}, sep[4]  = {0,0,0,0};
    float st[4]  = {0,0,0,0}, set_[4] = {0,0,0,0}, cv[4] = {0,0,0,0};

    bf16x8 kc[8], kn[8];
    A1_LOADK(kc, 0);
    for (int kt = 0; kt < 32; kt += 2) {
        A1_LOADK(kn, kt + 1);       // in flight across body(kt)
        A1_BODY(kt, kc);
        A1_LOADK(kc, kt + 2);       // kt+2 <= 32, in flight across body(kt+1)
        A1_BODY(kt + 1, kn);
    }
    A1_BODY(32, kc);

    #pragma unroll
    for (int r = 0; r < 4; ++r) {
        #pragma unroll
        for (int m = 1; m < 16; m <<= 1) {
            sp[r]   += __shfl_xor(sp[r],   m, 64);
            sep[r]  += __shfl_xor(sep[r],  m, 64);
            st[r]   += __shfl_xor(st[r],   m, 64);
            set_[r] += __shfl_xor(set_[r], m, 64);
            cv[r]   += __shfl_xor(cv[r],   m, 64);
        }
    }
    if (l15 == 0) {
        #pragma unroll
        for (int r = 0; r < 4; ++r) {
            if (nrow[r] < NN) {
                float ep = __expf(sp[r] * (1.0f / NPATCH));
                float et = __expf(st[r] * (1.0f / NTAB));
                float ec = __expf(cv[r]);
                float s  = ep + et + ec;
                float4 o;
                o.x = ep / (s * (sep[r]  + EPSF));
                o.y = et / (s * (set_[r] + EPSF));
                o.z = ec / (s * (ec      + EPSF));
                o.w = 0.f;
                stats[bh*NPAD + nrow[r]] = o;
            }
        }
    }
}

// ---------------- attention pass 2: A + context (A_raw replay, no QK recompute) ----
// Reads A_raw (bit-identical to recompute), applies exp*coef, stores A (C-layout,
// coalesced), round-trips P through double-buffered LDS (1 barrier/kt), V fragments
// loaded directly from global. A_raw values prefetched 1 tile ahead.
#define A2_LOADV(dst, ktv) do {                                                    \
    _Pragma("unroll")                                                              \
    for (int c = 0; c < 4; ++c) {                                                  \
        int col_ = (ktv)*64 + c*16 + l15;                                          \
        bool vc_ = col_ < NN;                                                      \
        _Pragma("unroll")                                                          \
        for (int r = 0; r < 4; ++r)                                                \
            dst[c*4+r] = (vc_ && vr[r]) ? Araw[rbase[r] + col_] : 0.f;             \
    }                                                                              \
} while (0)

#define A2_BODY(ktv, vvv) do {                                                     \
    int buf_ = (ktv) & 1;                                                          \
    _Pragma("unroll")                                                              \
    for (int c = 0; c < 4; ++c) {                                                  \
        int col_ = (ktv)*64 + c*16 + l15;                                          \
        bool vc_ = col_ < NN;                                                      \
        _Pragma("unroll")                                                          \
        for (int r = 0; r < 4; ++r) {                                              \
            float av_ = 0.f;                                                       \
            if (vc_ && vr[r]) {                                                    \
                float coef_ = (col_ < NPATCH) ? cp[r]                              \
                            : (col_ < NPATCH+NTAB) ? ct4[r] : cc4[r];              \
                av_ = __expf(vvv[c*4+r]) * coef_;                                  \
                A[rbase[r] + col_] = av_;                                          \
            }                                                                      \
            Ps[buf_][w*16 + quad*4 + r][c*16 + l15] = (bf16)av_;                   \
        }                                                                          \
    }                                                                              \
    __syncthreads();                                                               \
    {                                                                              \
        bf16x8 pa0_ = *(const bf16x8*)&Ps[buf_][w*16 + l15][quad*8];               \
        bf16x8 pa1_ = *(const bf16x8*)&Ps[buf_][w*16 + l15][32 + quad*8];          \
        _Pragma("unroll")                                                          \
        for (int g = 0; g < 4; ++g) {                                              \
            bf16x8 v0_ = *(const bf16x8*)(vb + (size_t)(g*16)*NPAD + (ktv)*64);    \
            bf16x8 v1_ = *(const bf16x8*)(vb + (size_t)(g*16)*NPAD + (ktv)*64 + 32); \
            o[g] = __builtin_amdgcn_mfma_f32_16x16x32_bf16(pa0_, v0_, o[g], 0, 0, 0); \
            o[g] = __builtin_amdgcn_mfma_f32_16x16x32_bf16(pa1_, v1_, o[g], 0, 0, 0); \
        }                                                                          \
    }                                                                              \
} while (0)

__global__ __launch_bounds__(256) void k_attn2(
    const float* __restrict__ Araw, const float4* __restrict__ stats,
    const bf16* __restrict__ Vt,
    float* __restrict__ A, bf16* __restrict__ attn)
{
    __shared__ bf16 Ps[2][64][LDS_STRIDE];     // double-buffered P tile
    int t = threadIdx.x;
    int w = t >> 6, l = t & 63, l15 = l & 15, quad = l >> 4;
    int n0 = blockIdx.x * 64;
    int bh = blockIdx.y;

    int nrow[4]; bool vr[4]; size_t rbase[4];
    float cp[4], ct4[4], cc4[4];
    #pragma unroll
    for (int r = 0; r < 4; ++r) {
        nrow[r] = n0 + w*16 + quad*4 + r;
        vr[r] = nrow[r] < NN;
        rbase[r] = ((size_t)(bh*NN + nrow[r]))*NN;
        float4 s4 = {0.f, 0.f, 0.f, 0.f};
        if (vr[r]) s4 = stats[bh*NPAD + nrow[r]];
        cp[r] = s4.x; ct4[r] = s4.y; cc4[r] = s4.z;
    }

    // per-lane V base: d-row = g*16 + l15, elem = kt*64 + kh*32 + quad*8
    const bf16* vb = Vt + (size_t)(bh*64)*NPAD + (size_t)(l15)*NPAD + quad*8;

    f32x4 o[4] = {};
    float vv[16], nv[16];

    A2_LOADV(vv, 0);
    for (int kt = 0; kt < 32; kt += 2) {
        A2_LOADV(nv, kt + 1);       // in flight across exp/LDS/barrier/MFMA of kt
        A2_BODY(kt, vv);
        A2_LOADV(vv, kt + 2);       // kt+2 <= 32
        A2_BODY(kt + 1, nv);
    }
    A2_BODY(32, vv);

    int b_ = bh >> 3, h = bh & 7;
    #pragma unroll
    for (int g = 0; g < 4; ++g) {
        #pragma unroll
        for (int r = 0; r < 4; ++r) {
            int n = nrow[r];
            if (n < NN)
                attn[((size_t)(b_*NN + n))*512 + h*64 + g*16 + l15] = (bf16)o[g][r];
        }
    }
}

// ---------------- GEMM2: out = attn @ w_out + b_out ----------------
__global__ __launch_bounds__(256) void k_gemm_out(
    const bf16* __restrict__ attn, const bf16* __restrict__ wt,
    const float* __restrict__ bias, float* __restrict__ out)
{
    __shared__ bf16 As[64][LDS_STRIDE];
    __shared__ bf16 Bs[64][LDS_STRIDE];
    int t = threadIdx.x;
    int w = t >> 6, l = t & 63, l15 = l & 15, quad = l >> 4;
    int m0 = blockIdx.y * 64, c0 = blockIdx.x * 64;
    int srow = t >> 2, sseg = (t & 3) * 16;
    f32x4 acc[4] = {};

    for (int kk = 0; kk < 512; kk += 64) {
        {
            int m = m0 + srow;
            uint4 v0 = {0,0,0,0}, v1 = {0,0,0,0};
            if (m < MROWS) {
                const uint4* src = (const uint4*)(attn + (size_t)m*512 + kk + sseg);
                v0 = src[0]; v1 = src[1];
            }
            *(uint4*)&As[srow][sseg]     = v0;
            *(uint4*)&As[srow][sseg + 8] = v1;
            const uint4* bs = (const uint4*)(wt + (size_t)(c0 + srow)*512 + kk + sseg);
            *(uint4*)&Bs[srow][sseg]     = bs[0];
            *(uint4*)&Bs[srow][sseg + 8] = bs[1];
        }
        __syncthreads();
        #pragma unroll
        for (int kh = 0; kh < 2; kh++) {
            bf16x8 a = *(const bf16x8*)&As[w*16 + l15][kh*32 + quad*8];
            #pragma unroll
            for (int c = 0; c < 4; c++) {
                bf16x8 b = *(const bf16x8*)&Bs[c*16 + l15][kh*32 + quad*8];
                acc[c] = __builtin_amdgcn_mfma_f32_16x16x32_bf16(a, b, acc[c], 0, 0, 0);
            }
        }
        __syncthreads();
    }
    #pragma unroll
    for (int c = 0; c < 4; c++) {
        int col = c0 + c*16 + l15;
        float bv = bias[col];
        #pragma unroll
        for (int r = 0; r < 4; r++) {
            int m = m0 + w*16 + quad*4 + r;
            if (m < MROWS)
                out[(size_t)m*512 + col] = acc[c][r] + bv;
        }
    }
}

// ---------------- launch ----------------
extern "C" void kernel_launch(void* const* d_in, const int* in_sizes, int n_in,
                              void* d_out, int out_size, void* d_ws, size_t ws_size,
                              hipStream_t stream)
{
    const float* x     = (const float*)d_in[0];
    const float* w_qkv = (const float*)d_in[1];
    const float* b_qkv = (const float*)d_in[2];
    const float* w_out = (const float*)d_in[3];
    const float* b_out = (const float*)d_in[4];

    float* out  = (float*)d_out;
    float* A    = out + (size_t)MROWS * 512;            // 2,114,560
    float* Araw = A   + (size_t)BB * HH * NN * NN;      // +68,227,600

    char* ws = (char*)d_ws;
    size_t off = 0;
    auto alloc = [&](size_t bytes) {
        char* p = ws + off;
        off += (bytes + 255) & ~(size_t)255;
        return p;
    };
    bf16*  xb    = (bf16*)alloc((size_t)MROWS * 512 * 2);
    bf16*  wqt   = (bf16*)alloc((size_t)1536 * 512 * 2);
    bf16*  wot   = (bf16*)alloc((size_t)512 * 512 * 2);
    bf16*  Qh    = (bf16*)alloc((size_t)16 * NPAD * 64 * 2);   // contiguous with
    bf16*  Kh    = (bf16*)alloc((size_t)16 * NPAD * 64 * 2);   // Kh, Vt (sizes are
    bf16*  Vt    = (bf16*)alloc((size_t)16 * NPAD * 64 * 2);   // multiples of 256)
    float4* stats = (float4*)alloc((size_t)16 * NPAD * 16);
    bf16*  attn  = (bf16*)alloc((size_t)MROWS * 512 * 2);
    (void)ws_size; (void)in_sizes; (void)n_in; (void)out_size;

    // zero the padded Q/K/V region (3 contiguous arrays)
    int zero4 = (int)((size_t)3 * 16 * NPAD * 64 * 2 / 16);    // 811,008 uint4
    k_zero<<<dim3((zero4 + 255) / 256), 256, 0, stream>>>((uint4*)Qh, zero4);

    k_cvt<<<dim3((MROWS*512/4 + 255) / 256), 256, 0, stream>>>(x, xb, MROWS*512/4);
    k_transcvt<<<dim3(1536*512/256), 256, 0, stream>>>(w_qkv, wqt, 1536, 1536*512);
    k_transcvt<<<dim3(512*512/256),  256, 0, stream>>>(w_out, wot, 512,  512*512);

    k_gemm_qkv<<<dim3(24, 65), 256, 0, stream>>>(xb, wqt, b_qkv, Qh, Kh, Vt);
    k_attn1<<<dim3(33, 16), 256, 0, stream>>>(Qh, Kh, Araw, stats);
    k_attn2<<<dim3(33, 16), 256, 0, stream>>>(Araw, stats, Vt, A, attn);
    k_gemm_out<<<dim3(8, 65), 256, 0, stream>>>(attn, wot, b_out, out);
}

// Round 3
// 988.623 us; speedup vs baseline: 1.0027x; 1.0027x over previous
//
#include <hip/hip_runtime.h>
#include <hip/hip_bf16.h>

// ---------------- problem constants ----------------
#define BB     2
#define NN     2065          // N_PATCH + N_TABLE + N_CLS
#define NPAD   2112          // 33*64
#define HH     8
#define DD     64
#define EE     512
#define MROWS  (BB*NN)       // 4130
#define NPATCH 2048
#define NTAB   16
#define SCALEF 0.125f
#define EPSF   1e-6f

typedef __bf16 bf16;
typedef bf16  bf16x8 __attribute__((ext_vector_type(8)));
typedef bf16  bf16x4v __attribute__((ext_vector_type(4)));
typedef float f32x4  __attribute__((ext_vector_type(4)));

// unaligned-tolerant float4 (A_raw/A rows have odd stride 2065 -> only 4B aligned)
struct __attribute__((packed, aligned(4))) f4p { float v[4]; };

#define LDS_STRIDE 72   // 64 + 8 pad bf16 (144 B rows, 16B aligned)

// ---------------- prep kernels ----------------
__global__ __launch_bounds__(256) void k_zero(uint4* __restrict__ p, int n4) {
    int i = blockIdx.x * 256 + threadIdx.x;
    if (i < n4) { uint4 z = {0,0,0,0}; p[i] = z; }
}

__global__ __launch_bounds__(256) void k_cvt(const float* __restrict__ x,
                                             bf16* __restrict__ o, int n4) {
    int i = blockIdx.x * 256 + threadIdx.x;
    if (i < n4) {
        float4 v = ((const float4*)x)[i];
        bf16x4v r;
        r[0] = (bf16)v.x; r[1] = (bf16)v.y; r[2] = (bf16)v.z; r[3] = (bf16)v.w;
        *(bf16x4v*)(o + 4*(size_t)i) = r;
    }
}

// out[c*512 + k] = in[k*C + c]   (weights have 512 rows)
__global__ __launch_bounds__(256) void k_transcvt(const float* __restrict__ w,
                                                  bf16* __restrict__ o,
                                                  int C, int total) {
    int i = blockIdx.x * 256 + threadIdx.x;
    if (i < total) {
        int k = i & 511, c = i >> 9;
        o[i] = (bf16)w[(size_t)k * C + c];
    }
}

// ---------------- GEMM1: qkv = x @ w_qkv + b ; scatter into Qh/Kh/Vt ----------------
__global__ __launch_bounds__(256) void k_gemm_qkv(
    const bf16* __restrict__ xb, const bf16* __restrict__ wt,
    const float* __restrict__ bias,
    bf16* __restrict__ Qh, bf16* __restrict__ Kh, bf16* __restrict__ Vt)
{
    __shared__ bf16 As[64][LDS_STRIDE];
    __shared__ bf16 Bs[64][LDS_STRIDE];
    int t = threadIdx.x;
    int w = t >> 6, l = t & 63, l15 = l & 15, quad = l >> 4;
    int m0 = blockIdx.y * 64, c0 = blockIdx.x * 64;
    int srow = t >> 2, sseg = (t & 3) * 16;
    f32x4 acc[4] = {};

    for (int kk = 0; kk < 512; kk += 64) {
        {
            int m = m0 + srow;
            uint4 v0 = {0,0,0,0}, v1 = {0,0,0,0};
            if (m < MROWS) {
                const uint4* src = (const uint4*)(xb + (size_t)m*512 + kk + sseg);
                v0 = src[0]; v1 = src[1];
            }
            *(uint4*)&As[srow][sseg]     = v0;
            *(uint4*)&As[srow][sseg + 8] = v1;
            const uint4* bs = (const uint4*)(wt + (size_t)(c0 + srow)*512 + kk + sseg);
            *(uint4*)&Bs[srow][sseg]     = bs[0];
            *(uint4*)&Bs[srow][sseg + 8] = bs[1];
        }
        __syncthreads();
        #pragma unroll
        for (int kh = 0; kh < 2; kh++) {
            bf16x8 a = *(const bf16x8*)&As[w*16 + l15][kh*32 + quad*8];
            #pragma unroll
            for (int c = 0; c < 4; c++) {
                bf16x8 b = *(const bf16x8*)&Bs[c*16 + l15][kh*32 + quad*8];
                acc[c] = __builtin_amdgcn_mfma_f32_16x16x32_bf16(a, b, acc[c], 0, 0, 0);
            }
        }
        __syncthreads();
    }

    int which = c0 >> 9;             // 0=q 1=k 2=v (uniform per block)
    int h = (c0 & 511) >> 6;         // uniform per block
    #pragma unroll
    for (int c = 0; c < 4; c++) {
        int d  = (c0 & 63) + c*16 + l15;   // c0 is mult of 64 -> d = c*16+l15
        float bv = bias[c0 + c*16 + l15];
        #pragma unroll
        for (int r = 0; r < 4; r++) {
            int m = m0 + w*16 + quad*4 + r;
            if (m >= MROWS) continue;
            int b_ = m / NN, n = m - b_ * NN;
            int bh = b_ * 8 + h;
            float v = acc[c][r] + bv;
            if (which == 0)      Qh[(size_t)(bh*NPAD + n)*64 + d] = (bf16)v;
            else if (which == 1) Kh[(size_t)(bh*NPAD + n)*64 + d] = (bf16)v;
            else                 Vt[((size_t)bh*64 + d)*NPAD + n] = (bf16)v;
        }
    }
}

// ---------------- attention pass 1: A_raw + per-row coefficients ----------------
__global__ __launch_bounds__(256) void k_attn1(
    const bf16* __restrict__ Qh, const bf16* __restrict__ Kh,
    float* __restrict__ Araw, float4* __restrict__ stats)
{
    __shared__ bf16 Qs[64][LDS_STRIDE];
    __shared__ bf16 Ks[64][LDS_STRIDE];
    int t = threadIdx.x;
    int w = t >> 6, l = t & 63, l15 = l & 15, quad = l >> 4;
    int n0 = blockIdx.x * 64;
    int bh = blockIdx.y;
    int srow = t >> 2, sseg = (t & 3) * 16;
    {
        const uint4* src = (const uint4*)(Qh + (size_t)(bh*NPAD + n0 + srow)*64 + sseg);
        *(uint4*)&Qs[srow][sseg]     = src[0];
        *(uint4*)&Qs[srow][sseg + 8] = src[1];
    }
    float sp[4]  = {0,0,0,0}, sep[4] = {0,0,0,0};
    float st[4]  = {0,0,0,0}, set_[4] = {0,0,0,0}, cv[4] = {0,0,0,0};
    int nrow[4];
    #pragma unroll
    for (int r = 0; r < 4; r++) nrow[r] = n0 + w*16 + quad*4 + r;

    for (int kt = 0; kt < 33; kt++) {
        __syncthreads();
        {
            const uint4* src = (const uint4*)(Kh + (size_t)(bh*NPAD + kt*64 + srow)*64 + sseg);
            *(uint4*)&Ks[srow][sseg]     = src[0];
            *(uint4*)&Ks[srow][sseg + 8] = src[1];
        }
        __syncthreads();
        f32x4 acc[4] = {};
        #pragma unroll
        for (int kh = 0; kh < 2; kh++) {
            bf16x8 a = *(const bf16x8*)&Qs[w*16 + l15][kh*32 + quad*8];
            #pragma unroll
            for (int c = 0; c < 4; c++) {
                bf16x8 b = *(const bf16x8*)&Ks[c*16 + l15][kh*32 + quad*8];
                acc[c] = __builtin_amdgcn_mfma_f32_16x16x32_bf16(a, b, acc[c], 0, 0, 0);
            }
        }
        #pragma unroll
        for (int c = 0; c < 4; c++) {
            int col = kt*64 + c*16 + l15;
            #pragma unroll
            for (int r = 0; r < 4; r++) {
                float val = acc[c][r] * SCALEF;
                float e = __expf(val);
                if (col < NPATCH)            { sp[r] += val; sep[r] += e; }
                else if (col < NPATCH+NTAB)  { st[r] += val; set_[r] += e; }
                else if (col == NPATCH+NTAB) { cv[r] = val; }
                if (col < NN && nrow[r] < NN)
                    Araw[((size_t)(bh*NN + nrow[r]))*NN + col] = val;
            }
        }
    }
    #pragma unroll
    for (int r = 0; r < 4; r++) {
        #pragma unroll
        for (int m = 1; m < 16; m <<= 1) {
            sp[r]   += __shfl_xor(sp[r],   m, 64);
            sep[r]  += __shfl_xor(sep[r],  m, 64);
            st[r]   += __shfl_xor(st[r],   m, 64);
            set_[r] += __shfl_xor(set_[r], m, 64);
            cv[r]   += __shfl_xor(cv[r],   m, 64);
        }
    }
    if (l15 == 0) {
        #pragma unroll
        for (int r = 0; r < 4; r++) {
            if (nrow[r] < NN) {
                float ep = __expf(sp[r] * (1.0f / NPATCH));
                float et = __expf(st[r] * (1.0f / NTAB));
                float ec = __expf(cv[r]);
                float s  = ep + et + ec;
                float4 o;
                o.x = ep / (s * (sep[r]  + EPSF));
                o.y = et / (s * (set_[r] + EPSF));
                o.z = ec / (s * (ec      + EPSF));
                o.w = 0.f;
                stats[bh*NPAD + nrow[r]] = o;
            }
        }
    }
}

// ---------------- attention pass 2: replay A_raw -> A + context ----------------
// No QK recompute: reads the f32 scores attn1 stored (bit-identical), applies
// exp(val)*coef, stores A (vector), packs P to LDS, runs the unchanged PV MFMA
// on staged Vs. 1-deep register prefetch of next tile's A_raw + V rides across
// the barrier + MFMA phase.
__global__ __launch_bounds__(256) void k_attn2(
    const float* __restrict__ Araw, const float4* __restrict__ stats,
    const bf16* __restrict__ Vt,
    float* __restrict__ A, bf16* __restrict__ attn)
{
    __shared__ bf16 Ps[64][LDS_STRIDE];
    __shared__ bf16 Vs[64][LDS_STRIDE];
    __shared__ float sCp[64], sCt[64], sCc[64];

    int t = threadIdx.x;
    int w = t >> 6, l = t & 63, l15 = l & 15, quad = l >> 4;
    int n0 = blockIdx.x * 64;
    int bh = blockIdx.y;
    int pr = t >> 2;              // staging row 0..63 (4 threads per row)
    int ps = (t & 3) * 16;        // 16-element column segment

    if (t < 64) {
        bool v = (n0 + t) < NN;
        float4 s4 = {0.f, 0.f, 0.f, 0.f};
        if (v) s4 = stats[bh*NPAD + n0 + t];
        sCp[t] = v ? s4.x : 0.f;
        sCt[t] = v ? s4.y : 0.f;
        sCc[t] = v ? s4.z : 0.f;
    }
    __syncthreads();
    float cpr = sCp[pr], ctr = sCt[pr], ccr = sCc[pr];

    bool prv = (n0 + pr) < NN;
    size_t arow = ((size_t)(bh*NN) + n0 + pr) * NN;               // valid iff prv
    const bf16* vrow = Vt + ((size_t)(bh*64) + pr) * NPAD;        // d-row pr

#define LOAD_A(dst, ktv) do {                                                  \
    _Pragma("unroll")                                                          \
    for (int j = 0; j < 4; ++j) {                                              \
        int c0_ = (ktv)*64 + ps + j*4;                                         \
        f4p v_ = {{0.f, 0.f, 0.f, 0.f}};                                       \
        if (prv) {                                                             \
            if (c0_ + 3 < NN) v_ = *(const f4p*)(Araw + arow + c0_);           \
            else {                                                             \
                if (c0_     < NN) v_.v[0] = Araw[arow + c0_];                  \
                if (c0_ + 1 < NN) v_.v[1] = Araw[arow + c0_ + 1];              \
                if (c0_ + 2 < NN) v_.v[2] = Araw[arow + c0_ + 2];              \
                if (c0_ + 3 < NN) v_.v[3] = Araw[arow + c0_ + 3];              \
            }                                                                  \
        }                                                                      \
        dst[j] = v_;                                                           \
    }                                                                          \
} while (0)

#define LOAD_V(dst, ktv) do {                                                  \
    const uint4* vp_ = (const uint4*)(vrow + (ktv)*64 + ps);                   \
    dst[0] = vp_[0]; dst[1] = vp_[1];                                          \
} while (0)

#define STAGE_PA(a4v, ktv) do {                                                \
    bf16x8 pb0_, pb1_;                                                         \
    _Pragma("unroll")                                                          \
    for (int j = 0; j < 4; ++j) {                                              \
        int c0_ = (ktv)*64 + ps + j*4;                                         \
        f4p av_;                                                               \
        _Pragma("unroll")                                                      \
        for (int e = 0; e < 4; ++e) {                                          \
            int c_ = c0_ + e;                                                  \
            float coef_ = (c_ < NPATCH) ? cpr                                  \
                        : (c_ < NPATCH+NTAB) ? ctr                             \
                        : (c_ == NPATCH+NTAB) ? ccr : 0.f;                     \
            float a_ = __expf(a4v[j].v[e]) * coef_;                            \
            av_.v[e] = a_;                                                     \
            if (j < 2) pb0_[j*4+e] = (bf16)a_;                                 \
            else       pb1_[(j-2)*4+e] = (bf16)a_;                             \
        }                                                                      \
        if (prv) {                                                             \
            if (c0_ + 3 < NN) *(f4p*)(A + arow + c0_) = av_;                   \
            else {                                                             \
                if (c0_     < NN) A[arow + c0_    ] = av_.v[0];                \
                if (c0_ + 1 < NN) A[arow + c0_ + 1] = av_.v[1];                \
                if (c0_ + 2 < NN) A[arow + c0_ + 2] = av_.v[2];                \
                if (c0_ + 3 < NN) A[arow + c0_ + 3] = av_.v[3];                \
            }                                                                  \
        }                                                                      \
    }                                                                          \
    *(bf16x8*)&Ps[pr][ps]     = pb0_;                                          \
    *(bf16x8*)&Ps[pr][ps + 8] = pb1_;                                          \
} while (0)

    f32x4 o[4] = {};
    f4p   a4[4];
    uint4 v4[2];
    LOAD_A(a4, 0);
    LOAD_V(v4, 0);

    #pragma unroll 1
    for (int kt = 0; kt < 33; ++kt) {
        *(uint4*)&Vs[pr][ps]     = v4[0];
        *(uint4*)&Vs[pr][ps + 8] = v4[1];
        STAGE_PA(a4, kt);
        if (kt < 32) {               // prefetch next tile; lands under barrier+MFMA
            LOAD_A(a4, kt + 1);
            LOAD_V(v4, kt + 1);
        }
        __syncthreads();
        #pragma unroll
        for (int kh = 0; kh < 2; kh++) {
            bf16x8 pa = *(const bf16x8*)&Ps[w*16 + l15][kh*32 + quad*8];
            #pragma unroll
            for (int g = 0; g < 4; g++) {
                bf16x8 vb = *(const bf16x8*)&Vs[g*16 + l15][kh*32 + quad*8];
                o[g] = __builtin_amdgcn_mfma_f32_16x16x32_bf16(pa, vb, o[g], 0, 0, 0);
            }
        }
        __syncthreads();
    }

    int b_ = bh >> 3, h = bh & 7;
    #pragma unroll
    for (int g = 0; g < 4; ++g) {
        #pragma unroll
        for (int r = 0; r < 4; ++r) {
            int n = n0 + w*16 + quad*4 + r;
            if (n < NN)
                attn[((size_t)(b_*NN + n))*512 + h*64 + g*16 + l15] = (bf16)o[g][r];
        }
    }
#undef LOAD_A
#undef LOAD_V
#undef STAGE_PA
}

// ---------------- GEMM2: out = attn @ w_out + b_out ----------------
__global__ __launch_bounds__(256) void k_gemm_out(
    const bf16* __restrict__ attn, const bf16* __restrict__ wt,
    const float* __restrict__ bias, float* __restrict__ out)
{
    __shared__ bf16 As[64][LDS_STRIDE];
    __shared__ bf16 Bs[64][LDS_STRIDE];
    int t = threadIdx.x;
    int w = t >> 6, l = t & 63, l15 = l & 15, quad = l >> 4;
    int m0 = blockIdx.y * 64, c0 = blockIdx.x * 64;
    int srow = t >> 2, sseg = (t & 3) * 16;
    f32x4 acc[4] = {};

    for (int kk = 0; kk < 512; kk += 64) {
        {
            int m = m0 + srow;
            uint4 v0 = {0,0,0,0}, v1 = {0,0,0,0};
            if (m < MROWS) {
                const uint4* src = (const uint4*)(attn + (size_t)m*512 + kk + sseg);
                v0 = src[0]; v1 = src[1];
            }
            *(uint4*)&As[srow][sseg]     = v0;
            *(uint4*)&As[srow][sseg + 8] = v1;
            const uint4* bs = (const uint4*)(wt + (size_t)(c0 + srow)*512 + kk + sseg);
            *(uint4*)&Bs[srow][sseg]     = bs[0];
            *(uint4*)&Bs[srow][sseg + 8] = bs[1];
        }
        __syncthreads();
        #pragma unroll
        for (int kh = 0; kh < 2; kh++) {
            bf16x8 a = *(const bf16x8*)&As[w*16 + l15][kh*32 + quad*8];
            #pragma unroll
            for (int c = 0; c < 4; c++) {
                bf16x8 b = *(const bf16x8*)&Bs[c*16 + l15][kh*32 + quad*8];
                acc[c] = __builtin_amdgcn_mfma_f32_16x16x32_bf16(a, b, acc[c], 0, 0, 0);
            }
        }
        __syncthreads();
    }
    #pragma unroll
    for (int c = 0; c < 4; c++) {
        int col = c0 + c*16 + l15;
        float bv = bias[col];
        #pragma unroll
        for (int r = 0; r < 4; r++) {
            int m = m0 + w*16 + quad*4 + r;
            if (m < MROWS)
                out[(size_t)m*512 + col] = acc[c][r] + bv;
        }
    }
}

// ---------------- launch ----------------
extern "C" void kernel_launch(void* const* d_in, const int* in_sizes, int n_in,
                              void* d_out, int out_size, void* d_ws, size_t ws_size,
                              hipStream_t stream)
{
    const float* x     = (const float*)d_in[0];
    const float* w_qkv = (const float*)d_in[1];
    const float* b_qkv = (const float*)d_in[2];
    const float* w_out = (const float*)d_in[3];
    const float* b_out = (const float*)d_in[4];

    float* out  = (float*)d_out;
    float* A    = out + (size_t)MROWS * 512;            // 2,114,560
    float* Araw = A   + (size_t)BB * HH * NN * NN;      // +68,227,600

    char* ws = (char*)d_ws;
    size_t off = 0;
    auto alloc = [&](size_t bytes) {
        char* p = ws + off;
        off += (bytes + 255) & ~(size_t)255;
        return p;
    };
    bf16*  xb    = (bf16*)alloc((size_t)MROWS * 512 * 2);
    bf16*  wqt   = (bf16*)alloc((size_t)1536 * 512 * 2);
    bf16*  wot   = (bf16*)alloc((size_t)512 * 512 * 2);
    bf16*  Qh    = (bf16*)alloc((size_t)16 * NPAD * 64 * 2);   // contiguous with
    bf16*  Kh    = (bf16*)alloc((size_t)16 * NPAD * 64 * 2);   // Kh, Vt (sizes are
    bf16*  Vt    = (bf16*)alloc((size_t)16 * NPAD * 64 * 2);   // multiples of 256)
    float4* stats = (float4*)alloc((size_t)16 * NPAD * 16);
    bf16*  attn  = (bf16*)alloc((size_t)MROWS * 512 * 2);
    (void)ws_size; (void)in_sizes; (void)n_in; (void)out_size;

    // zero the padded Q/K/V region (3 contiguous arrays)
    int zero4 = (int)((size_t)3 * 16 * NPAD * 64 * 2 / 16);    // 811,008 uint4
    k_zero<<<dim3((zero4 + 255) / 256), 256, 0, stream>>>((uint4*)Qh, zero4);

    k_cvt<<<dim3((MROWS*512/4 + 255) / 256), 256, 0, stream>>>(x, xb, MROWS*512/4);
    k_transcvt<<<dim3(1536*512/256), 256, 0, stream>>>(w_qkv, wqt, 1536, 1536*512);
    k_transcvt<<<dim3(512*512/256),  256, 0, stream>>>(w_out, wot, 512,  512*512);

    k_gemm_qkv<<<dim3(24, 65), 256, 0, stream>>>(xb, wqt, b_qkv, Qh, Kh, Vt);
    k_attn1<<<dim3(33, 16), 256, 0, stream>>>(Qh, Kh, Araw, stats);
    k_attn2<<<dim3(33, 16), 256, 0, stream>>>(Araw, stats, Vt, A, attn);
    k_gemm_out<<<dim3(8, 65), 256, 0, stream>>>(attn, wot, b_out, out);
}

// Round 4
// 744.543 us; speedup vs baseline: 1.3314x; 1.3278x over previous
//
#include <hip/hip_runtime.h>
#include <hip/hip_bf16.h>

// ---------------- problem constants ----------------
#define BB     2
#define NN     2065          // N_PATCH + N_TABLE + N_CLS
#define NPAD   2112          // 33*64
#define HH     8
#define DD     64
#define EE     512
#define MROWS  (BB*NN)       // 4130
#define NPATCH 2048
#define NTAB   16
#define SCALEF 0.125f
#define EPSF   1e-6f

typedef __bf16 bf16;
typedef bf16  bf16x8 __attribute__((ext_vector_type(8)));
typedef bf16  bf16x4v __attribute__((ext_vector_type(4)));
typedef float f32x4  __attribute__((ext_vector_type(4)));

#define LDS_STRIDE 72   // 64 + 8 pad bf16 (144 B rows, 16B aligned)

// ---------------- prep kernels ----------------
__global__ __launch_bounds__(256) void k_zero(uint4* __restrict__ p, int n4) {
    int i = blockIdx.x * 256 + threadIdx.x;
    if (i < n4) { uint4 z = {0,0,0,0}; p[i] = z; }
}

__global__ __launch_bounds__(256) void k_cvt(const float* __restrict__ x,
                                             bf16* __restrict__ o, int n4) {
    int i = blockIdx.x * 256 + threadIdx.x;
    if (i < n4) {
        float4 v = ((const float4*)x)[i];
        bf16x4v r;
        r[0] = (bf16)v.x; r[1] = (bf16)v.y; r[2] = (bf16)v.z; r[3] = (bf16)v.w;
        *(bf16x4v*)(o + 4*(size_t)i) = r;
    }
}

// out[c*512 + k] = in[k*C + c]   (weights have 512 rows)
__global__ __launch_bounds__(256) void k_transcvt(const float* __restrict__ w,
                                                  bf16* __restrict__ o,
                                                  int C, int total) {
    int i = blockIdx.x * 256 + threadIdx.x;
    if (i < total) {
        int k = i & 511, c = i >> 9;
        o[i] = (bf16)w[(size_t)k * C + c];
    }
}

// ---------------- GEMM1: qkv = x @ w_qkv + b ; scatter into Qh/Kh/Vt ----------------
__global__ __launch_bounds__(256) void k_gemm_qkv(
    const bf16* __restrict__ xb, const bf16* __restrict__ wt,
    const float* __restrict__ bias,
    bf16* __restrict__ Qh, bf16* __restrict__ Kh, bf16* __restrict__ Vt)
{
    __shared__ bf16 As[64][LDS_STRIDE];
    __shared__ bf16 Bs[64][LDS_STRIDE];
    int t = threadIdx.x;
    int w = t >> 6, l = t & 63, l15 = l & 15, quad = l >> 4;
    int m0 = blockIdx.y * 64, c0 = blockIdx.x * 64;
    int srow = t >> 2, sseg = (t & 3) * 16;
    f32x4 acc[4] = {};

    for (int kk = 0; kk < 512; kk += 64) {
        {
            int m = m0 + srow;
            uint4 v0 = {0,0,0,0}, v1 = {0,0,0,0};
            if (m < MROWS) {
                const uint4* src = (const uint4*)(xb + (size_t)m*512 + kk + sseg);
                v0 = src[0]; v1 = src[1];
            }
            *(uint4*)&As[srow][sseg]     = v0;
            *(uint4*)&As[srow][sseg + 8] = v1;
            const uint4* bs = (const uint4*)(wt + (size_t)(c0 + srow)*512 + kk + sseg);
            *(uint4*)&Bs[srow][sseg]     = bs[0];
            *(uint4*)&Bs[srow][sseg + 8] = bs[1];
        }
        __syncthreads();
        #pragma unroll
        for (int kh = 0; kh < 2; kh++) {
            bf16x8 a = *(const bf16x8*)&As[w*16 + l15][kh*32 + quad*8];
            #pragma unroll
            for (int c = 0; c < 4; c++) {
                bf16x8 b = *(const bf16x8*)&Bs[c*16 + l15][kh*32 + quad*8];
                acc[c] = __builtin_amdgcn_mfma_f32_16x16x32_bf16(a, b, acc[c], 0, 0, 0);
            }
        }
        __syncthreads();
    }

    int which = c0 >> 9;             // 0=q 1=k 2=v (uniform per block)
    int h = (c0 & 511) >> 6;         // uniform per block
    #pragma unroll
    for (int c = 0; c < 4; c++) {
        int d  = (c0 & 63) + c*16 + l15;   // c0 is mult of 64 -> d = c*16+l15
        float bv = bias[c0 + c*16 + l15];
        #pragma unroll
        for (int r = 0; r < 4; r++) {
            int m = m0 + w*16 + quad*4 + r;
            if (m >= MROWS) continue;
            int b_ = m / NN, n = m - b_ * NN;
            int bh = b_ * 8 + h;
            float v = acc[c][r] + bv;
            if (which == 0)      Qh[(size_t)(bh*NPAD + n)*64 + d] = (bf16)v;
            else if (which == 1) Kh[(size_t)(bh*NPAD + n)*64 + d] = (bf16)v;
            else                 Vt[((size_t)bh*64 + d)*NPAD + n] = (bf16)v;
        }
    }
}

// ---------------- attention pass 1: A_raw + per-row coefficients ----------------
// 32-row blocks (grid 66x16 = 1056 -> 4 blocks/CU x 4 waves = 16 waves/CU),
// register-staged double-buffered K (load kt+2 issued at iter kt, LDS-write after
// MFMA+epilogue), ONE barrier per kt. Wave w: rows (w&1)*16, col-half (w>>1)*32.
__global__ __launch_bounds__(256) void k_attn1(
    const bf16* __restrict__ Qh, const bf16* __restrict__ Kh,
    float* __restrict__ Araw, float4* __restrict__ stats)
{
    __shared__ bf16 Qs[32][LDS_STRIDE];
    __shared__ bf16 Ks[2][64][LDS_STRIDE];
    __shared__ float sRed[2][32][6];      // [colhalf][row][{sp,sep,st,set,cv}+pad]

    int t = threadIdx.x;
    int w = t >> 6, l = t & 63, l15 = l & 15, quad = l >> 4;
    int n0 = blockIdx.x * 32;
    int bh = blockIdx.y;
    int r0 = (w & 1) * 16;               // wave's row offset within the 32-row tile
    int ch = (w >> 1);                   // wave's col half (0/1) -> cols ch*32 + c*16

    // stage Q (32 rows x 64 cols): thread t -> row t>>3, 8-elem seg (t&7)*8
    {
        int qrow = t >> 3, qseg = (t & 7) * 8;
        *(uint4*)&Qs[qrow][qseg] =
            *(const uint4*)(Qh + ((size_t)bh*NPAD + n0 + qrow)*64 + qseg);
    }

    // K staging geometry: 64 rows x 64 cols, thread t -> row t>>2, 16-elem seg
    int krow = t >> 2, kseg = (t & 3) * 16;
    const bf16* kbase = Kh + ((size_t)bh*NPAD)*64 + (size_t)krow*64 + kseg;
    uint4 kv0, kv1;

    // prologue: tile 0 -> LDS buf0; tile 1 load in flight
    {
        const uint4* s = (const uint4*)(kbase);
        kv0 = s[0]; kv1 = s[1];
        *(uint4*)&Ks[0][krow][kseg]     = kv0;
        *(uint4*)&Ks[0][krow][kseg + 8] = kv1;
        const uint4* s1 = (const uint4*)(kbase + (size_t)64*64);
        kv0 = s1[0]; kv1 = s1[1];
    }
    __syncthreads();                      // Qs + Ks[0] visible

    // Q fragments are loop-invariant: hoist
    bf16x8 qa0 = *(const bf16x8*)&Qs[r0 + l15][quad*8];
    bf16x8 qa1 = *(const bf16x8*)&Qs[r0 + l15][32 + quad*8];

    int nrow[4]; bool vr[4]; size_t rbase[4];
    #pragma unroll
    for (int r = 0; r < 4; ++r) {
        nrow[r] = n0 + quad*4 + r;        // rows within wave tile: r0 + quad*4 + r
        nrow[r] += r0;
        vr[r] = nrow[r] < NN;
        rbase[r] = ((size_t)(bh*NN) + nrow[r]) * NN;
    }

    float sp[4]  = {0,0,0,0}, sep[4]  = {0,0,0,0};
    float st[4]  = {0,0,0,0}, set_[4] = {0,0,0,0}, cv[4] = {0,0,0,0};

    for (int kt = 0; kt < 33; ++kt) {
        int cur = kt & 1;
        f32x4 acc[2] = {};
        #pragma unroll
        for (int c = 0; c < 2; ++c) {
            bf16x8 b0 = *(const bf16x8*)&Ks[cur][ch*32 + c*16 + l15][quad*8];
            bf16x8 b1 = *(const bf16x8*)&Ks[cur][ch*32 + c*16 + l15][32 + quad*8];
            acc[c] = __builtin_amdgcn_mfma_f32_16x16x32_bf16(qa0, b0, acc[c], 0, 0, 0);
            acc[c] = __builtin_amdgcn_mfma_f32_16x16x32_bf16(qa1, b1, acc[c], 0, 0, 0);
        }
        // epilogue: stats + scalar Araw stores (no sector-misaligned wide stores)
        #pragma unroll
        for (int c = 0; c < 2; ++c) {
            int col = kt*64 + ch*32 + c*16 + l15;
            bool colNN = col < NN;
            #pragma unroll
            for (int r = 0; r < 4; ++r) {
                float val = acc[c][r] * SCALEF;
                float e = __expf(val);
                if (col < NPATCH)            { sp[r] += val; sep[r] += e; }
                else if (col < NPATCH+NTAB)  { st[r] += val; set_[r] += e; }
                else if (col == NPATCH+NTAB) { cv[r] = val; }
                if (colNN && vr[r])
                    Araw[rbase[r] + col] = val;
            }
        }
        // write-late: next K tile regs -> LDS (other buffer), then issue kt+2 load
        if (kt < 32) {
            *(uint4*)&Ks[cur ^ 1][krow][kseg]     = kv0;
            *(uint4*)&Ks[cur ^ 1][krow][kseg + 8] = kv1;
        }
        if (kt < 31) {
            const uint4* s = (const uint4*)(kbase + (size_t)(kt + 2)*64*64);
            kv0 = s[0]; kv1 = s[1];
        }
        __syncthreads();                  // one barrier per kt
    }

    // reduce over the 16 l15 lanes (quad bits untouched by masks 1,2,4,8)
    #pragma unroll
    for (int r = 0; r < 4; ++r) {
        #pragma unroll
        for (int m = 1; m < 16; m <<= 1) {
            sp[r]   += __shfl_xor(sp[r],   m, 64);
            sep[r]  += __shfl_xor(sep[r],  m, 64);
            st[r]   += __shfl_xor(st[r],   m, 64);
            set_[r] += __shfl_xor(set_[r], m, 64);
            cv[r]   += __shfl_xor(cv[r],   m, 64);
        }
    }
    if (l15 == 0) {
        #pragma unroll
        for (int r = 0; r < 4; ++r) {
            int row = r0 + quad*4 + r;
            sRed[ch][row][0] = sp[r];
            sRed[ch][row][1] = sep[r];
            sRed[ch][row][2] = st[r];
            sRed[ch][row][3] = set_[r];
            sRed[ch][row][4] = cv[r];
        }
    }
    __syncthreads();
    if (t < 32) {
        int n = n0 + t;
        if (n < NN) {
            float spt  = sRed[0][t][0] + sRed[1][t][0];
            float sept = sRed[0][t][1] + sRed[1][t][1];
            float stt  = sRed[0][t][2] + sRed[1][t][2];
            float sett = sRed[0][t][3] + sRed[1][t][3];
            float cvt_ = sRed[0][t][4] + sRed[1][t][4];
            float ep = __expf(spt * (1.0f / NPATCH));
            float et = __expf(stt * (1.0f / NTAB));
            float ec = __expf(cvt_);
            float s  = ep + et + ec;
            float4 o;
            o.x = ep / (s * (sept + EPSF));
            o.y = et / (s * (sett + EPSF));
            o.z = ec / (s * (ec   + EPSF));
            o.w = 0.f;
            stats[bh*NPAD + n] = o;
        }
    }
}

// ---------------- attention pass 2: A + context (round-0 structure) ----------------
__global__ __launch_bounds__(256) void k_attn2(
    const bf16* __restrict__ Qh, const bf16* __restrict__ Kh,
    const bf16* __restrict__ Vt, const float4* __restrict__ stats,
    float* __restrict__ A, bf16* __restrict__ attn)
{
    __shared__ bf16 Qs[64][LDS_STRIDE];
    __shared__ bf16 Ks[64][LDS_STRIDE];
    __shared__ bf16 Vs[64][LDS_STRIDE];
    __shared__ bf16 Ps[64][LDS_STRIDE];
    int t = threadIdx.x;
    int w = t >> 6, l = t & 63, l15 = l & 15, quad = l >> 4;
    int n0 = blockIdx.x * 64;
    int bh = blockIdx.y;
    int srow = t >> 2, sseg = (t & 3) * 16;
    {
        const uint4* src = (const uint4*)(Qh + (size_t)(bh*NPAD + n0 + srow)*64 + sseg);
        *(uint4*)&Qs[srow][sseg]     = src[0];
        *(uint4*)&Qs[srow][sseg + 8] = src[1];
    }
    int nrow[4];
    float cp[4], ctb[4], cc[4];
    #pragma unroll
    for (int r = 0; r < 4; r++) {
        nrow[r] = n0 + w*16 + quad*4 + r;
        float4 s4 = stats[bh*NPAD + nrow[r]];
        cp[r] = s4.x; ctb[r] = s4.y; cc[r] = s4.z;
    }
    f32x4 o[4] = {};

    for (int kt = 0; kt < 33; kt++) {
        __syncthreads();
        {
            const uint4* ks = (const uint4*)(Kh + (size_t)(bh*NPAD + kt*64 + srow)*64 + sseg);
            *(uint4*)&Ks[srow][sseg]     = ks[0];
            *(uint4*)&Ks[srow][sseg + 8] = ks[1];
            const uint4* vs = (const uint4*)(Vt + ((size_t)bh*64 + srow)*NPAD + kt*64 + sseg);
            *(uint4*)&Vs[srow][sseg]     = vs[0];
            *(uint4*)&Vs[srow][sseg + 8] = vs[1];
        }
        __syncthreads();
        f32x4 acc[4] = {};
        #pragma unroll
        for (int kh = 0; kh < 2; kh++) {
            bf16x8 a = *(const bf16x8*)&Qs[w*16 + l15][kh*32 + quad*8];
            #pragma unroll
            for (int c = 0; c < 4; c++) {
                bf16x8 b = *(const bf16x8*)&Ks[c*16 + l15][kh*32 + quad*8];
                acc[c] = __builtin_amdgcn_mfma_f32_16x16x32_bf16(a, b, acc[c], 0, 0, 0);
            }
        }
        #pragma unroll
        for (int c = 0; c < 4; c++) {
            int col = kt*64 + c*16 + l15;
            #pragma unroll
            for (int r = 0; r < 4; r++) {
                float val = acc[c][r] * SCALEF;
                float e = __expf(val);
                float coef = (col < NPATCH) ? cp[r]
                           : (col < NPATCH+NTAB) ? ctb[r]
                           : (col == NPATCH+NTAB) ? cc[r] : 0.f;
                float av = e * coef;
                if (col < NN && nrow[r] < NN)
                    A[((size_t)(bh*NN + nrow[r]))*NN + col] = av;
                Ps[w*16 + quad*4 + r][c*16 + l15] = (bf16)av;
            }
        }
        __syncthreads();
        #pragma unroll
        for (int kh = 0; kh < 2; kh++) {
            bf16x8 pa = *(const bf16x8*)&Ps[w*16 + l15][kh*32 + quad*8];
            #pragma unroll
            for (int g = 0; g < 4; g++) {
                bf16x8 vb = *(const bf16x8*)&Vs[g*16 + l15][kh*32 + quad*8];
                o[g] = __builtin_amdgcn_mfma_f32_16x16x32_bf16(pa, vb, o[g], 0, 0, 0);
            }
        }
    }
    int b_ = bh >> 3, h = bh & 7;
    #pragma unroll
    for (int g = 0; g < 4; g++) {
        #pragma unroll
        for (int r = 0; r < 4; r++) {
            int n = nrow[r];
            if (n < NN)
                attn[((size_t)(b_*NN + n))*512 + h*64 + g*16 + l15] = (bf16)o[g][r];
        }
    }
}

// ---------------- GEMM2: out = attn @ w_out + b_out ----------------
__global__ __launch_bounds__(256) void k_gemm_out(
    const bf16* __restrict__ attn, const bf16* __restrict__ wt,
    const float* __restrict__ bias, float* __restrict__ out)
{
    __shared__ bf16 As[64][LDS_STRIDE];
    __shared__ bf16 Bs[64][LDS_STRIDE];
    int t = threadIdx.x;
    int w = t >> 6, l = t & 63, l15 = l & 15, quad = l >> 4;
    int m0 = blockIdx.y * 64, c0 = blockIdx.x * 64;
    int srow = t >> 2, sseg = (t & 3) * 16;
    f32x4 acc[4] = {};

    for (int kk = 0; kk < 512; kk += 64) {
        {
            int m = m0 + srow;
            uint4 v0 = {0,0,0,0}, v1 = {0,0,0,0};
            if (m < MROWS) {
                const uint4* src = (const uint4*)(attn + (size_t)m*512 + kk + sseg);
                v0 = src[0]; v1 = src[1];
            }
            *(uint4*)&As[srow][sseg]     = v0;
            *(uint4*)&As[srow][sseg + 8] = v1;
            const uint4* bs = (const uint4*)(wt + (size_t)(c0 + srow)*512 + kk + sseg);
            *(uint4*)&Bs[srow][sseg]     = bs[0];
            *(uint4*)&Bs[srow][sseg + 8] = bs[1];
        }
        __syncthreads();
        #pragma unroll
        for (int kh = 0; kh < 2; kh++) {
            bf16x8 a = *(const bf16x8*)&As[w*16 + l15][kh*32 + quad*8];
            #pragma unroll
            for (int c = 0; c < 4; c++) {
                bf16x8 b = *(const bf16x8*)&Bs[c*16 + l15][kh*32 + quad*8];
                acc[c] = __builtin_amdgcn_mfma_f32_16x16x32_bf16(a, b, acc[c], 0, 0, 0);
            }
        }
        __syncthreads();
    }
    #pragma unroll
    for (int c = 0; c < 4; c++) {
        int col = c0 + c*16 + l15;
        float bv = bias[col];
        #pragma unroll
        for (int r = 0; r < 4; r++) {
            int m = m0 + w*16 + quad*4 + r;
            if (m < MROWS)
                out[(size_t)m*512 + col] = acc[c][r] + bv;
        }
    }
}

// ---------------- launch ----------------
extern "C" void kernel_launch(void* const* d_in, const int* in_sizes, int n_in,
                              void* d_out, int out_size, void* d_ws, size_t ws_size,
                              hipStream_t stream)
{
    const float* x     = (const float*)d_in[0];
    const float* w_qkv = (const float*)d_in[1];
    const float* b_qkv = (const float*)d_in[2];
    const float* w_out = (const float*)d_in[3];
    const float* b_out = (const float*)d_in[4];

    float* out  = (float*)d_out;
    float* A    = out + (size_t)MROWS * 512;            // 2,114,560
    float* Araw = A   + (size_t)BB * HH * NN * NN;      // +68,227,600

    char* ws = (char*)d_ws;
    size_t off = 0;
    auto alloc = [&](size_t bytes) {
        char* p = ws + off;
        off += (bytes + 255) & ~(size_t)255;
        return p;
    };
    bf16*  xb    = (bf16*)alloc((size_t)MROWS * 512 * 2);
    bf16*  wqt   = (bf16*)alloc((size_t)1536 * 512 * 2);
    bf16*  wot   = (bf16*)alloc((size_t)512 * 512 * 2);
    bf16*  Qh    = (bf16*)alloc((size_t)16 * NPAD * 64 * 2);   // contiguous with
    bf16*  Kh    = (bf16*)alloc((size_t)16 * NPAD * 64 * 2);   // Kh, Vt (sizes are
    bf16*  Vt    = (bf16*)alloc((size_t)16 * NPAD * 64 * 2);   // multiples of 256)
    float4* stats = (float4*)alloc((size_t)16 * NPAD * 16);
    bf16*  attn  = (bf16*)alloc((size_t)MROWS * 512 * 2);
    (void)ws_size; (void)in_sizes; (void)n_in; (void)out_size;

    // zero the padded Q/K/V region (3 contiguous arrays)
    int zero4 = (int)((size_t)3 * 16 * NPAD * 64 * 2 / 16);    // 811,008 uint4
    k_zero<<<dim3((zero4 + 255) / 256), 256, 0, stream>>>((uint4*)Qh, zero4);

    k_cvt<<<dim3((MROWS*512/4 + 255) / 256), 256, 0, stream>>>(x, xb, MROWS*512/4);
    k_transcvt<<<dim3(1536*512/256), 256, 0, stream>>>(w_qkv, wqt, 1536, 1536*512);
    k_transcvt<<<dim3(512*512/256),  256, 0, stream>>>(w_out, wot, 512,  512*512);

    k_gemm_qkv<<<dim3(24, 65), 256, 0, stream>>>(xb, wqt, b_qkv, Qh, Kh, Vt);
    k_attn1<<<dim3(66, 16), 256, 0, stream>>>(Qh, Kh, Araw, stats);
    k_attn2<<<dim3(33, 16), 256, 0, stream>>>(Qh, Kh, Vt, stats, A, attn);
    k_gemm_out<<<dim3(8, 65), 256, 0, stream>>>(attn, wot, b_out, out);
}